// Round 2
// baseline (204.374 us; speedup 1.0000x reference)
//
#include <hip/hip_runtime.h>

typedef __attribute__((ext_vector_type(8))) short short8;
typedef __attribute__((ext_vector_type(4))) float floatx4;
typedef __attribute__((ext_vector_type(4))) float float4v;
typedef __attribute__((ext_vector_type(4))) unsigned short ushort4v;

static __device__ __forceinline__ unsigned short f2bf(float x) {
    unsigned int u = __builtin_bit_cast(unsigned int, x);
    unsigned int r = (u + 0x7FFFu + ((u >> 16) & 1u)) >> 16;
    return (unsigned short)r;
}

// One prep launch: tables fp32->bf16 (vectorized) + W1 [256k][128n] -> w1t [128n][256k] bf16
// + zero-init out (atomicAdd accumulates onto it; re-inits every graph replay).
__global__ void prep_all(const float* __restrict__ zd, const float* __restrict__ zs,
                         const float* __restrict__ W1,
                         int nd4, int ns4, int e4,
                         unsigned short* __restrict__ outd, unsigned short* __restrict__ outs,
                         unsigned short* __restrict__ w1t, float* __restrict__ out0) {
    int i = blockIdx.x * 256 + threadIdx.x;
    int total4 = nd4 + ns4;
    if (i < total4) {
        const float* src; unsigned short* dst; int j;
        if (i < nd4) { src = zd; dst = outd; j = i; }
        else         { src = zs; dst = outs; j = i - nd4; }
        float4v v = *reinterpret_cast<const float4v*>(src + (size_t)j * 4);
        ushort4v o;
        o.x = f2bf(v.x); o.y = f2bf(v.y); o.z = f2bf(v.z); o.w = f2bf(v.w);
        *reinterpret_cast<ushort4v*>(dst + (size_t)j * 4) = o;
    } else {
        int j = i - total4;
        if (j < 128 * 256) {
            int n = j >> 8;
            int k = j & 255;
            w1t[n * 256 + k] = f2bf(W1[k * 128 + n]);
        } else {
            int j2 = j - 128 * 256;
            if (j2 < e4) {
                float4v z4 = {0.f, 0.f, 0.f, 0.f};
                *reinterpret_cast<float4v*>(out0 + (size_t)j2 * 4) = z4;
            }
        }
    }
}

// Direct-gather edge MLP: no LDS tile, no barriers, no DMA staging.
// One wave per 64-thread block. Each wave owns one hidden-half (wfrag = 128 VGPRs)
// and a stream of 32-edge groups. B-fragments for mfma_16x16x32_bf16
// (lane: col = l15, k = quad*8+j) are gathered DIRECTLY from the bf16 tables:
//   addr = table[idx[et*16+l15]] * 256B + s*64 + quad*16
// -> one global_load_dwordx4 per (s,et), 16 unique 64B lines, L2/L3-resident (6.4 MB).
// The two hidden-half waves of a group atomicAdd their partial dot onto out[] (0-init).
// Pairing map keeps both halves 8 blockIdx apart -> same XCD -> shared L2 lines.
//
// Per-group pipeline (in-wave, vmcnt-counted by compiler, never drained):
//   issue drug gathers (s0..3) -> idx prefetch (g+1) -> epilogue(g-1) [covers latency]
//   -> acc init (= b1, bias folded) -> MFMA s0..1 -> issue disease gathers (s4..7)
//   -> MFMA s2..7 -> loop.
__global__ __launch_bounds__(64, 2) void edge_mlp(
    const unsigned short* __restrict__ zd, const unsigned short* __restrict__ zs,
    const int* __restrict__ row, const int* __restrict__ col,
    const unsigned short* __restrict__ w1t,
    const float* __restrict__ b1, const float* __restrict__ w2,
    const float* __restrict__ b2, float* __restrict__ out, int ng)
{
    const int lane = threadIdx.x;        // one wave per block
    const int l15  = lane & 15;
    const int quad = lane >> 4;

    const int b = blockIdx.x;
    const int half   = (b >> 3) & 1;                 // hidden half
    const int stream = (b & 7) | ((b >> 4) << 3);    // 0..1023, pair b/b^8 same stream+XCD
    const int whbase = half * 64;

    // ---- persistent W1 A-fragments (128 VGPRs): A[m=whbase+mt*16+l15][k=s*32+quad*8+j]
    short8 wfrag[32];                    // [s*4 + mt]
    #pragma unroll
    for (int s = 0; s < 8; ++s)
        #pragma unroll
        for (int mt = 0; mt < 4; ++mt)
            wfrag[s * 4 + mt] = *reinterpret_cast<const short8*>(
                &w1t[(size_t)(whbase + mt * 16 + l15) * 256 + s * 32 + quad * 8]);

    // ---- epilogue constants (32 VGPRs): rows m = whbase + mt*16 + quad*4 + rr
    floatx4 b1v[4], w2v[4];
    #pragma unroll
    for (int mt = 0; mt < 4; ++mt) {
        b1v[mt] = *reinterpret_cast<const floatx4*>(&b1[whbase + mt * 16 + quad * 4]);
        w2v[mt] = *reinterpret_cast<const floatx4*>(&w2[whbase + mt * 16 + quad * 4]);
    }
    const float badd = (half == 0) ? b2[0] : 0.0f;   // b2 added exactly once per edge

    const long gbase = (long)stream * ng;

    // ---- prologue: indices for first group
    int r0 = row[gbase * 32 + l15];
    int r1 = row[gbase * 32 + 16 + l15];
    int c0 = col[gbase * 32 + l15];
    int c1 = col[gbase * 32 + 16 + l15];
    int rn0, rn1, cn0, cn1;

    floatx4 acc[2][4];                   // [et][mt]

#define EPI(gprev)                                                             \
    {                                                                          \
        float p00 = 0.f, p01 = 0.f, p10 = 0.f, p11 = 0.f;                      \
        _Pragma("unroll")                                                      \
        for (int mt = 0; mt < 4; ++mt)                                         \
            _Pragma("unroll")                                                  \
            for (int rr = 0; rr < 4; ++rr) {                                   \
                float h0 = acc[0][mt][rr]; h0 = h0 > 0.f ? h0 : 0.f;           \
                float h1 = acc[1][mt][rr]; h1 = h1 > 0.f ? h1 : 0.f;           \
                if (rr & 1) { p01 += h0 * w2v[mt][rr]; p11 += h1 * w2v[mt][rr]; } \
                else        { p00 += h0 * w2v[mt][rr]; p10 += h1 * w2v[mt][rr]; } \
            }                                                                  \
        float v0 = p00 + p01, v1 = p10 + p11;                                  \
        v0 += __shfl_xor(v0, 16); v0 += __shfl_xor(v0, 32);                    \
        v1 += __shfl_xor(v1, 16); v1 += __shfl_xor(v1, 32);                    \
        float vv = (lane & 16) ? v1 : v0;                                      \
        if (lane < 32) atomicAdd(&out[(gprev) * 32 + lane], vv + badd);        \
    }

    for (int i = 0; i < ng; ++i) {
        const long g = gbase + i;

        // (1) drug-half gathers for this group (k = 0..127), 8 instrs
        short8 bA[4][2];
        #pragma unroll
        for (int s = 0; s < 4; ++s) {
            bA[s][0] = *reinterpret_cast<const short8*>(&zd[(size_t)r0 * 128 + s * 32 + quad * 8]);
            bA[s][1] = *reinterpret_cast<const short8*>(&zd[(size_t)r1 * 128 + s * 32 + quad * 8]);
        }

        // (2) index prefetch for next group (full K-loop of slack)
        {
            long gn = (i + 1 < ng) ? (g + 1) : gbase;
            rn0 = row[gn * 32 + l15];
            rn1 = row[gn * 32 + 16 + l15];
            cn0 = col[gn * 32 + l15];
            cn1 = col[gn * 32 + 16 + l15];
        }

        // (3) epilogue of previous group — hides bA gather latency
        if (i > 0) EPI(g - 1)

        // (4) acc init = b1 (bias folded into the MFMA C-operand)
        #pragma unroll
        for (int et = 0; et < 2; ++et)
            #pragma unroll
            for (int mt = 0; mt < 4; ++mt)
                acc[et][mt] = b1v[mt];

        // (5) MFMA s0..1 on drug fragments
        __builtin_amdgcn_s_setprio(1);
        #pragma unroll
        for (int s = 0; s < 2; ++s)
            #pragma unroll
            for (int et = 0; et < 2; ++et)
                #pragma unroll
                for (int mt = 0; mt < 4; ++mt)
                    acc[et][mt] = __builtin_amdgcn_mfma_f32_16x16x32_bf16(
                        wfrag[s * 4 + mt], bA[s][et], acc[et][mt], 0, 0, 0);
        __builtin_amdgcn_s_setprio(0);

        // (6) disease-half gathers (k = 128..255) — latency hidden under s2..3 MFMAs
        short8 bB[4][2];
        #pragma unroll
        for (int s = 0; s < 4; ++s) {
            bB[s][0] = *reinterpret_cast<const short8*>(&zs[(size_t)c0 * 128 + s * 32 + quad * 8]);
            bB[s][1] = *reinterpret_cast<const short8*>(&zs[(size_t)c1 * 128 + s * 32 + quad * 8]);
        }

        // (7) MFMA s2..3 (drug) + s4..7 (disease)
        __builtin_amdgcn_s_setprio(1);
        #pragma unroll
        for (int s = 2; s < 4; ++s)
            #pragma unroll
            for (int et = 0; et < 2; ++et)
                #pragma unroll
                for (int mt = 0; mt < 4; ++mt)
                    acc[et][mt] = __builtin_amdgcn_mfma_f32_16x16x32_bf16(
                        wfrag[s * 4 + mt], bA[s][et], acc[et][mt], 0, 0, 0);
        #pragma unroll
        for (int s = 0; s < 4; ++s)
            #pragma unroll
            for (int et = 0; et < 2; ++et)
                #pragma unroll
                for (int mt = 0; mt < 4; ++mt)
                    acc[et][mt] = __builtin_amdgcn_mfma_f32_16x16x32_bf16(
                        wfrag[(s + 4) * 4 + mt], bB[s][et], acc[et][mt], 0, 0, 0);
        __builtin_amdgcn_s_setprio(0);

        r0 = rn0; r1 = rn1; c0 = cn0; c1 = cn1;
    }

    // drain: epilogue of last group
    EPI(gbase + ng - 1)
#undef EPI
}

extern "C" void kernel_launch(void* const* d_in, const int* in_sizes, int n_in,
                              void* d_out, int out_size, void* d_ws, size_t ws_size,
                              hipStream_t stream) {
    const float* zd = (const float*)d_in[0];
    const float* zs = (const float*)d_in[1];
    const int*   row = (const int*)d_in[2];
    const int*   col = (const int*)d_in[3];
    const float* W1 = (const float*)d_in[4];
    const float* b1 = (const float*)d_in[5];
    const float* w2 = (const float*)d_in[6];
    const float* b2 = (const float*)d_in[7];
    float* out = (float*)d_out;

    const int nd = in_sizes[0];   // 10000*128
    const int ns = in_sizes[1];   // 15000*128
    const int E  = in_sizes[2];   // 1048576

    unsigned short* zd_b = (unsigned short*)d_ws;
    unsigned short* zs_b = zd_b + nd;
    unsigned short* w1t  = zs_b + ns;   // 128*256 bf16

    const int total_jobs = (nd + ns) / 4 + 128 * 256 + E / 4;
    const int pgrid = (total_jobs + 255) / 256;
    hipLaunchKernelGGL(prep_all, dim3(pgrid), dim3(256), 0, stream,
                       zd, zs, W1, nd / 4, ns / 4, E / 4, zd_b, zs_b, w1t, out);

    const int nstreams = 1024;           // 2048 waves = 2/SIMD, pairs (b, b^8) share a group stream
    const int ng = (E / 32) / nstreams;  // 32 groups per stream
    hipLaunchKernelGGL(edge_mlp, dim3(2 * nstreams), dim3(64), 0, stream,
                       zd_b, zs_b, row, col, w1t, b1, w2, b2, out, ng);
}

// Round 3
// 142.673 us; speedup vs baseline: 1.4325x; 1.4325x over previous
//
#include <hip/hip_runtime.h>

typedef __attribute__((ext_vector_type(8))) short short8;
typedef __attribute__((ext_vector_type(4))) float floatx4;
typedef _Float16 half8 __attribute__((ext_vector_type(8)));
typedef _Float16 half4 __attribute__((ext_vector_type(4)));

static __device__ __forceinline__ unsigned short f2bf(float x) {
    unsigned int u = __builtin_bit_cast(unsigned int, x);
    unsigned int r = (u + 0x7FFFu + ((u >> 16) & 1u)) >> 16;
    return (unsigned short)r;
}

// W1 [256k][128n] -> w1t [128n][256k] bf16 (same transposed layout the MFMA A-frags use)
__global__ void prep_w1(const float* __restrict__ W1, unsigned short* __restrict__ w1t) {
    int i = blockIdx.x * 256 + threadIdx.x;   // grid covers exactly 128*256
    int n = i >> 8;
    int k = i & 255;
    w1t[n * 256 + k] = f2bf(W1[k * 128 + n]);
}

// Factorized precompute: ud[i] = zd[i] @ W1[0:128]  + 0.5*b1   (10000 x 128, fp16)
//                        us[j] = zs[j] @ W1[128:256] + 0.5*b1  (15000 x 128, fp16)
// One block = 64 rows of one table, all 128 hidden. 4 waves: wave -> (hidden half wh,
// row half we). Same verified fragment convention as the old edge_mlp:
//   A (W1T): m = wh*64 + mt*16 + l15, k = koff0 + s*32 + quad*8 + j   (regs, 64 VGPR)
//   B (z):   r = m0 + we*32 + et*16 + l15, same k; fp32 loaded, f2bf inline
//   acc[et][mt][rr]: row r as above, h = wh*64 + mt*16 + quad*4 + rr
__global__ __launch_bounds__(256, 2) void factor_gemm(
    const float* __restrict__ zd, const float* __restrict__ zs,
    const unsigned short* __restrict__ w1t, const float* __restrict__ b1,
    _Float16* __restrict__ ud, _Float16* __restrict__ us,
    int ndrows, int nsrows, int ntd)
{
    const int tid  = threadIdx.x;
    const int lane = tid & 63;
    const int wave = tid >> 6;
    const int wh   = wave >> 1;
    const int we   = wave & 1;
    const int l15  = lane & 15;
    const int quad = lane >> 4;

    const int b = blockIdx.x;
    const bool isD = (b < ntd);
    const float* __restrict__ z = isD ? zd : zs;
    _Float16* __restrict__ u = isD ? ud : us;
    const int nrows = isD ? ndrows : nsrows;
    const int m0    = (isD ? b : b - ntd) * 64;
    const int koff0 = isD ? 0 : 128;

    short8 wfrag[16];
    #pragma unroll
    for (int s = 0; s < 4; ++s)
        #pragma unroll
        for (int mt = 0; mt < 4; ++mt)
            wfrag[s * 4 + mt] = *reinterpret_cast<const short8*>(
                &w1t[(size_t)(wh * 64 + mt * 16 + l15) * 256 + koff0 + s * 32 + quad * 8]);

    floatx4 acc[2][4];
    #pragma unroll
    for (int mt = 0; mt < 4; ++mt) {
        floatx4 bb = *reinterpret_cast<const floatx4*>(&b1[wh * 64 + mt * 16 + quad * 4]);
        bb *= 0.5f;                       // each half contributes b1/2 -> sum = b1
        acc[0][mt] = bb;
        acc[1][mt] = bb;
    }

    int rowi[2], rowc[2];
    #pragma unroll
    for (int et = 0; et < 2; ++et) {
        rowi[et] = m0 + we * 32 + et * 16 + l15;
        rowc[et] = rowi[et] < nrows ? rowi[et] : nrows - 1;   // clamp tail loads
    }

    #pragma unroll
    for (int s = 0; s < 4; ++s) {
        short8 bf[2];
        #pragma unroll
        for (int et = 0; et < 2; ++et) {
            const float* src = &z[(size_t)rowc[et] * 128 + s * 32 + quad * 8];
            floatx4 lo = *reinterpret_cast<const floatx4*>(src);
            floatx4 hi = *reinterpret_cast<const floatx4*>(src + 4);
            short8 t;
            t[0] = (short)f2bf(lo[0]); t[1] = (short)f2bf(lo[1]);
            t[2] = (short)f2bf(lo[2]); t[3] = (short)f2bf(lo[3]);
            t[4] = (short)f2bf(hi[0]); t[5] = (short)f2bf(hi[1]);
            t[6] = (short)f2bf(hi[2]); t[7] = (short)f2bf(hi[3]);
            bf[et] = t;
        }
        #pragma unroll
        for (int et = 0; et < 2; ++et)
            #pragma unroll
            for (int mt = 0; mt < 4; ++mt)
                acc[et][mt] = __builtin_amdgcn_mfma_f32_16x16x32_bf16(
                    wfrag[s * 4 + mt], bf[et], acc[et][mt], 0, 0, 0);
    }

    #pragma unroll
    for (int et = 0; et < 2; ++et) {
        if (rowi[et] < nrows) {
            #pragma unroll
            for (int mt = 0; mt < 4; ++mt) {
                half4 hv;
                #pragma unroll
                for (int rr = 0; rr < 4; ++rr) hv[rr] = (_Float16)acc[et][mt][rr];
                *reinterpret_cast<half4*>(
                    &u[(size_t)rowi[et] * 128 + wh * 64 + mt * 16 + quad * 4]) = hv;
            }
        }
    }
}

// Edge phase: out[e] = w2 . relu(ud[row[e]] + us[col[e]]) + b2.
// 4 lanes per edge (q = lane&3 owns h = q*32..q*32+31), 16 edges per wave per iter.
// Pure gather + VALU: packed fp16 add/relu, f32 dot, 2-shuffle reduce, direct store.
// ~85 VGPR -> 5 waves/SIMD; TLP hides the idx->u/v dependent-gather latency.
__global__ __launch_bounds__(256, 4) void edge_eval(
    const _Float16* __restrict__ ud, const _Float16* __restrict__ us,
    const int* __restrict__ row, const int* __restrict__ col,
    const float* __restrict__ w2, const float* __restrict__ b2,
    float* __restrict__ out, int nchunks)
{
    const int tid  = threadIdx.x;
    const int lane = tid & 63;
    const int wave = tid >> 6;
    const int le   = lane >> 2;          // edge slot 0..15
    const int q    = lane & 3;           // hidden quarter

    float w2r[32];
    #pragma unroll
    for (int i = 0; i < 8; ++i)
        *reinterpret_cast<floatx4*>(&w2r[i * 4]) =
            *reinterpret_cast<const floatx4*>(&w2[q * 32 + i * 4]);
    const float b2v = b2[0];

    const int G = gridDim.x;
    long t = blockIdx.x;
    if (t >= nchunks) return;
    long eg = t * 64 + wave * 16 + le;
    int r = row[eg], c = col[eg];

    while (t < nchunks) {
        // (1) issue this iter's gathers first (4+4 x 16B per lane, 8 lines/edge)
        const _Float16* up = ud + (size_t)r * 128 + q * 32;
        const _Float16* vp = us + (size_t)c * 128 + q * 32;
        half8 uu[4], vv[4];
        #pragma unroll
        for (int i = 0; i < 4; ++i) {
            uu[i] = *reinterpret_cast<const half8*>(up + i * 8);
            vv[i] = *reinterpret_cast<const half8*>(vp + i * 8);
        }

        // (2) prefetch next iter's indices (hides idx->gather chain)
        long tn = t + G;
        int rn = 0, cn = 0;
        if (tn < nchunks) {
            long egn = tn * 64 + wave * 16 + le;
            rn = row[egn];
            cn = col[egn];
        }

        // (3) packed add + relu (v_pk_*_f16), f32 dot with w2
        float acc = 0.f;
        #pragma unroll
        for (int i = 0; i < 4; ++i) {
            half8 s8 = uu[i] + vv[i];
            s8 = __builtin_elementwise_max(s8, (half8)(_Float16)0.f);
            #pragma unroll
            for (int j = 0; j < 8; ++j)
                acc += (float)s8[j] * w2r[i * 8 + j];
        }

        // (4) reduce the 4 hidden-quarters, one writer per edge
        acc += __shfl_xor(acc, 1);
        acc += __shfl_xor(acc, 2);
        if (q == 0) out[eg] = acc + b2v;

        t = tn;
        eg = tn * 64 + wave * 16 + le;
        r = rn; c = cn;
    }
}

extern "C" void kernel_launch(void* const* d_in, const int* in_sizes, int n_in,
                              void* d_out, int out_size, void* d_ws, size_t ws_size,
                              hipStream_t stream) {
    const float* zd = (const float*)d_in[0];
    const float* zs = (const float*)d_in[1];
    const int*   row = (const int*)d_in[2];
    const int*   col = (const int*)d_in[3];
    const float* W1 = (const float*)d_in[4];
    const float* b1 = (const float*)d_in[5];
    const float* w2 = (const float*)d_in[6];
    const float* b2 = (const float*)d_in[7];
    float* out = (float*)d_out;

    const int nd = in_sizes[0];   // 10000*128
    const int ns = in_sizes[1];   // 15000*128
    const int E  = in_sizes[2];   // 1048576
    const int ndrows = nd / 128;
    const int nsrows = ns / 128;

    // workspace: w1t (64 KB) | ud fp16 (ndrows*128) | us fp16 (nsrows*128) = 6.47 MB
    unsigned short* w1t = (unsigned short*)d_ws;
    _Float16* ud = (_Float16*)((char*)d_ws + 128 * 256 * sizeof(unsigned short));
    _Float16* us = ud + (size_t)ndrows * 128;

    hipLaunchKernelGGL(prep_w1, dim3(128), dim3(256), 0, stream, W1, w1t);

    const int ntd = (ndrows + 63) / 64;   // 157
    const int nts = (nsrows + 63) / 64;   // 235
    hipLaunchKernelGGL(factor_gemm, dim3(ntd + nts), dim3(256), 0, stream,
                       zd, zs, w1t, b1, ud, us, ndrows, nsrows, ntd);

    const int nchunks = E / 64;           // 16384
    const int egrid = nchunks < 2048 ? nchunks : 2048;
    hipLaunchKernelGGL(edge_eval, dim3(egrid), dim3(256), 0, stream,
                       ud, us, row, col, w2, b2, out, nchunks);
}

// Round 4
// 126.411 us; speedup vs baseline: 1.6167x; 1.1287x over previous
//
#include <hip/hip_runtime.h>

typedef __attribute__((ext_vector_type(8))) short short8;
typedef __attribute__((ext_vector_type(4))) float floatx4;
typedef _Float16 half8 __attribute__((ext_vector_type(8)));
typedef _Float16 half4 __attribute__((ext_vector_type(4)));

static __device__ __forceinline__ unsigned short f2bf(float x) {
    unsigned int u = __builtin_bit_cast(unsigned int, x);
    unsigned int r = (u + 0x7FFFu + ((u >> 16) & 1u)) >> 16;
    return (unsigned short)r;
}

// W1 [256k][128n] -> w1t [128n][256k] bf16 (same transposed layout the MFMA A-frags use)
__global__ void prep_w1(const float* __restrict__ W1, unsigned short* __restrict__ w1t) {
    int i = blockIdx.x * 256 + threadIdx.x;   // grid covers exactly 128*256
    int n = i >> 8;
    int k = i & 255;
    w1t[n * 256 + k] = f2bf(W1[k * 128 + n]);
}

// Factorized precompute: ud[i] = zd[i] @ W1[0:128]  + 0.5*b1   (10000 x 128, fp16)
//                        us[j] = zs[j] @ W1[128:256] + 0.5*b1  (15000 x 128, fp16)
__global__ __launch_bounds__(256, 2) void factor_gemm(
    const float* __restrict__ zd, const float* __restrict__ zs,
    const unsigned short* __restrict__ w1t, const float* __restrict__ b1,
    _Float16* __restrict__ ud, _Float16* __restrict__ us,
    int ndrows, int nsrows, int ntd)
{
    const int tid  = threadIdx.x;
    const int lane = tid & 63;
    const int wave = tid >> 6;
    const int wh   = wave >> 1;
    const int we   = wave & 1;
    const int l15  = lane & 15;
    const int quad = lane >> 4;

    const int b = blockIdx.x;
    const bool isD = (b < ntd);
    const float* __restrict__ z = isD ? zd : zs;
    _Float16* __restrict__ u = isD ? ud : us;
    const int nrows = isD ? ndrows : nsrows;
    const int m0    = (isD ? b : b - ntd) * 64;
    const int koff0 = isD ? 0 : 128;

    short8 wfrag[16];
    #pragma unroll
    for (int s = 0; s < 4; ++s)
        #pragma unroll
        for (int mt = 0; mt < 4; ++mt)
            wfrag[s * 4 + mt] = *reinterpret_cast<const short8*>(
                &w1t[(size_t)(wh * 64 + mt * 16 + l15) * 256 + koff0 + s * 32 + quad * 8]);

    floatx4 acc[2][4];
    #pragma unroll
    for (int mt = 0; mt < 4; ++mt) {
        floatx4 bb = *reinterpret_cast<const floatx4*>(&b1[wh * 64 + mt * 16 + quad * 4]);
        bb *= 0.5f;                       // each half contributes b1/2 -> sum = b1
        acc[0][mt] = bb;
        acc[1][mt] = bb;
    }

    int rowi[2], rowc[2];
    #pragma unroll
    for (int et = 0; et < 2; ++et) {
        rowi[et] = m0 + we * 32 + et * 16 + l15;
        rowc[et] = rowi[et] < nrows ? rowi[et] : nrows - 1;   // clamp tail loads
    }

    #pragma unroll
    for (int s = 0; s < 4; ++s) {
        short8 bf[2];
        #pragma unroll
        for (int et = 0; et < 2; ++et) {
            const float* src = &z[(size_t)rowc[et] * 128 + s * 32 + quad * 8];
            floatx4 lo = *reinterpret_cast<const floatx4*>(src);
            floatx4 hi = *reinterpret_cast<const floatx4*>(src + 4);
            short8 t;
            t[0] = (short)f2bf(lo[0]); t[1] = (short)f2bf(lo[1]);
            t[2] = (short)f2bf(lo[2]); t[3] = (short)f2bf(lo[3]);
            t[4] = (short)f2bf(hi[0]); t[5] = (short)f2bf(hi[1]);
            t[6] = (short)f2bf(hi[2]); t[7] = (short)f2bf(hi[3]);
            bf[et] = t;
        }
        #pragma unroll
        for (int et = 0; et < 2; ++et)
            #pragma unroll
            for (int mt = 0; mt < 4; ++mt)
                acc[et][mt] = __builtin_amdgcn_mfma_f32_16x16x32_bf16(
                    wfrag[s * 4 + mt], bf[et], acc[et][mt], 0, 0, 0);
    }

    #pragma unroll
    for (int et = 0; et < 2; ++et) {
        if (rowi[et] < nrows) {
            #pragma unroll
            for (int mt = 0; mt < 4; ++mt) {
                half4 hv;
                #pragma unroll
                for (int rr = 0; rr < 4; ++rr) hv[rr] = (_Float16)acc[et][mt][rr];
                *reinterpret_cast<half4*>(
                    &u[(size_t)rowi[et] * 128 + wh * 64 + mt * 16 + quad * 4]) = hv;
            }
        }
    }
}

// Edge phase v2: out[e] = w2 . relu(ud[row[e]] + us[col[e]]) + b2.
// 8 lanes per edge (le = lane>>3, q = lane&7). COALESCED gather: lane q reads
// bytes [i*128 + q*16) of the 256B row -> the 8 lanes of an edge cover two full
// contiguous 64B lines per instr (16 lines/instr, standard float4 shape), 4x fewer
// TA transactions than the q*64-strided layout. Lane's w2 slice permutes to match:
// w2r[i*8+j] = w2[i*64 + q*8 + j] (dot+shuffle reduction is permutation-invariant).
//
// Two-deep register double-buffer (A/B): gathers for chunk t+G are issued and
// indices for t+2G prefetched BEFORE computing chunk t, so every gather has a
// full compute phase of slack; ~80 VGPR -> ~6 waves/SIMD of TLP on top.
__global__ __launch_bounds__(256, 4) void edge_eval(
    const _Float16* __restrict__ ud, const _Float16* __restrict__ us,
    const int* __restrict__ row, const int* __restrict__ col,
    const float* __restrict__ w2, const float* __restrict__ b2,
    float* __restrict__ out, int nchunks)
{
    const int tid  = threadIdx.x;
    const int lane = tid & 63;
    const int wave = tid >> 6;
    const int le   = lane >> 3;          // edge slot 0..7
    const int q    = lane & 7;           // 16B sub-chunk 0..7
    const int lslot = wave * 8 + le;     // 0..31 within chunk

    float w2r[16];                       // w2[i*64 + q*8 + j]
    #pragma unroll
    for (int i = 0; i < 2; ++i) {
        *reinterpret_cast<floatx4*>(&w2r[i * 8]) =
            *reinterpret_cast<const floatx4*>(&w2[i * 64 + q * 8]);
        *reinterpret_cast<floatx4*>(&w2r[i * 8 + 4]) =
            *reinterpret_cast<const floatx4*>(&w2[i * 64 + q * 8 + 4]);
    }
    const float b2v = b2[0];
    const int G = gridDim.x;

    int t = blockIdx.x;
    if (t >= nchunks) return;

#define GATHER(U, V, rr, cc)                                                      \
    {                                                                             \
        _Pragma("unroll")                                                         \
        for (int i = 0; i < 2; ++i) {                                             \
            U[i] = *reinterpret_cast<const half8*>(&ud[(rr) * 128 + i * 64 + q * 8]); \
            V[i] = *reinterpret_cast<const half8*>(&us[(cc) * 128 + i * 64 + q * 8]); \
        }                                                                         \
    }

#define COMPUTE(U, V, tt)                                                         \
    {                                                                             \
        float acc = 0.f;                                                          \
        _Pragma("unroll")                                                         \
        for (int i = 0; i < 2; ++i) {                                             \
            half8 s8 = U[i] + V[i];                                               \
            s8 = __builtin_elementwise_max(s8, (half8)(_Float16)0.f);             \
            _Pragma("unroll")                                                     \
            for (int j = 0; j < 8; ++j)                                           \
                acc += (float)s8[j] * w2r[i * 8 + j];                             \
        }                                                                         \
        acc += __shfl_xor(acc, 1);                                                \
        acc += __shfl_xor(acc, 2);                                                \
        acc += __shfl_xor(acc, 4);                                                \
        if (q == 0) out[(tt) * 32 + lslot] = acc + b2v;                           \
    }

    // prologue: chunk t data in flight (A); indices for t+G ready (B)
    int rA = row[t * 32 + lslot], cA = col[t * 32 + lslot];
    half8 uA[2], vA[2], uB[2], vB[2];
    GATHER(uA, vA, rA, cA)
    int rB = 0, cB = 0;
    {
        int t1 = t + G;
        if (t1 < nchunks) { rB = row[t1 * 32 + lslot]; cB = col[t1 * 32 + lslot]; }
    }

    while (true) {
        const int tB = t + G, tA2 = t + 2 * G;

        // (1) issue B gathers (chunk t+G) — consumed after compute A
        if (tB < nchunks) GATHER(uB, vB, rB, cB)

        // (2) prefetch indices for chunk t+2G (used in step 4)
        int rA2 = 0, cA2 = 0;
        if (tA2 < nchunks) { rA2 = row[tA2 * 32 + lslot]; cA2 = col[tA2 * 32 + lslot]; }

        // (3) compute A -> out chunk t
        COMPUTE(uA, vA, t)

        if (tB >= nchunks) break;

        // (4) issue A gathers for chunk t+2G
        if (tA2 < nchunks) GATHER(uA, vA, rA2, cA2)

        // (5) prefetch indices for chunk t+3G (B-stage of next trip)
        {
            int t3 = t + 3 * G;
            rB = 0; cB = 0;
            if (t3 < nchunks) { rB = row[t3 * 32 + lslot]; cB = col[t3 * 32 + lslot]; }
        }

        // (6) compute B -> out chunk t+G
        COMPUTE(uB, vB, tB)

        if (tA2 >= nchunks) break;
        t = tA2;
    }
#undef GATHER
#undef COMPUTE
}

extern "C" void kernel_launch(void* const* d_in, const int* in_sizes, int n_in,
                              void* d_out, int out_size, void* d_ws, size_t ws_size,
                              hipStream_t stream) {
    const float* zd = (const float*)d_in[0];
    const float* zs = (const float*)d_in[1];
    const int*   row = (const int*)d_in[2];
    const int*   col = (const int*)d_in[3];
    const float* W1 = (const float*)d_in[4];
    const float* b1 = (const float*)d_in[5];
    const float* w2 = (const float*)d_in[6];
    const float* b2 = (const float*)d_in[7];
    float* out = (float*)d_out;

    const int nd = in_sizes[0];   // 10000*128
    const int ns = in_sizes[1];   // 15000*128
    const int E  = in_sizes[2];   // 1048576
    const int ndrows = nd / 128;
    const int nsrows = ns / 128;

    // workspace: w1t (64 KB) | ud fp16 | us fp16 = 6.47 MB
    unsigned short* w1t = (unsigned short*)d_ws;
    _Float16* ud = (_Float16*)((char*)d_ws + 128 * 256 * sizeof(unsigned short));
    _Float16* us = ud + (size_t)ndrows * 128;

    hipLaunchKernelGGL(prep_w1, dim3(128), dim3(256), 0, stream, W1, w1t);

    const int ntd = (ndrows + 63) / 64;   // 157
    const int nts = (nsrows + 63) / 64;   // 235
    hipLaunchKernelGGL(factor_gemm, dim3(ntd + nts), dim3(256), 0, stream,
                       zd, zs, w1t, b1, ud, us, ndrows, nsrows, ntd);

    const int nchunks = E / 32;           // 32768 chunks of 32 edges
    const int egrid = 2048;               // 16 chunks per block, even pipeline trips
    hipLaunchKernelGGL(edge_eval, dim3(egrid), dim3(256), 0, stream,
                       ud, us, row, col, w2, b2, out, nchunks);
}

// Round 5
// 126.316 us; speedup vs baseline: 1.6180x; 1.0008x over previous
//
#include <hip/hip_runtime.h>

typedef __attribute__((ext_vector_type(8))) short short8;
typedef __attribute__((ext_vector_type(4))) float floatx4;
typedef _Float16 half8 __attribute__((ext_vector_type(8)));
typedef _Float16 half4 __attribute__((ext_vector_type(4)));
typedef _Float16 half2v __attribute__((ext_vector_type(2)));

static __device__ __forceinline__ unsigned short f2bf(float x) {
    unsigned int u = __builtin_bit_cast(unsigned int, x);
    unsigned int r = (u + 0x7FFFu + ((u >> 16) & 1u)) >> 16;
    return (unsigned short)r;
}

// W1 [256k][128n] -> w1t [128n][256k] bf16 (same transposed layout the MFMA A-frags use)
__global__ void prep_w1(const float* __restrict__ W1, unsigned short* __restrict__ w1t) {
    int i = blockIdx.x * 256 + threadIdx.x;   // grid covers exactly 128*256
    int n = i >> 8;
    int k = i & 255;
    w1t[n * 256 + k] = f2bf(W1[k * 128 + n]);
}

// Factorized precompute: ud[i] = zd[i] @ W1[0:128]  + 0.5*b1   (10000 x 128, fp16)
//                        us[j] = zs[j] @ W1[128:256] + 0.5*b1  (15000 x 128, fp16)
__global__ __launch_bounds__(256, 2) void factor_gemm(
    const float* __restrict__ zd, const float* __restrict__ zs,
    const unsigned short* __restrict__ w1t, const float* __restrict__ b1,
    _Float16* __restrict__ ud, _Float16* __restrict__ us,
    int ndrows, int nsrows, int ntd)
{
    const int tid  = threadIdx.x;
    const int lane = tid & 63;
    const int wave = tid >> 6;
    const int wh   = wave >> 1;
    const int we   = wave & 1;
    const int l15  = lane & 15;
    const int quad = lane >> 4;

    const int b = blockIdx.x;
    const bool isD = (b < ntd);
    const float* __restrict__ z = isD ? zd : zs;
    _Float16* __restrict__ u = isD ? ud : us;
    const int nrows = isD ? ndrows : nsrows;
    const int m0    = (isD ? b : b - ntd) * 64;
    const int koff0 = isD ? 0 : 128;

    short8 wfrag[16];
    #pragma unroll
    for (int s = 0; s < 4; ++s)
        #pragma unroll
        for (int mt = 0; mt < 4; ++mt)
            wfrag[s * 4 + mt] = *reinterpret_cast<const short8*>(
                &w1t[(size_t)(wh * 64 + mt * 16 + l15) * 256 + koff0 + s * 32 + quad * 8]);

    floatx4 acc[2][4];
    #pragma unroll
    for (int mt = 0; mt < 4; ++mt) {
        floatx4 bb = *reinterpret_cast<const floatx4*>(&b1[wh * 64 + mt * 16 + quad * 4]);
        bb *= 0.5f;                       // each half contributes b1/2 -> sum = b1
        acc[0][mt] = bb;
        acc[1][mt] = bb;
    }

    int rowi[2], rowc[2];
    #pragma unroll
    for (int et = 0; et < 2; ++et) {
        rowi[et] = m0 + we * 32 + et * 16 + l15;
        rowc[et] = rowi[et] < nrows ? rowi[et] : nrows - 1;   // clamp tail loads
    }

    #pragma unroll
    for (int s = 0; s < 4; ++s) {
        short8 bf[2];
        #pragma unroll
        for (int et = 0; et < 2; ++et) {
            const float* src = &z[(size_t)rowc[et] * 128 + s * 32 + quad * 8];
            floatx4 lo = *reinterpret_cast<const floatx4*>(src);
            floatx4 hi = *reinterpret_cast<const floatx4*>(src + 4);
            short8 t;
            t[0] = (short)f2bf(lo[0]); t[1] = (short)f2bf(lo[1]);
            t[2] = (short)f2bf(lo[2]); t[3] = (short)f2bf(lo[3]);
            t[4] = (short)f2bf(hi[0]); t[5] = (short)f2bf(hi[1]);
            t[6] = (short)f2bf(hi[2]); t[7] = (short)f2bf(hi[3]);
            bf[et] = t;
        }
        #pragma unroll
        for (int et = 0; et < 2; ++et)
            #pragma unroll
            for (int mt = 0; mt < 4; ++mt)
                acc[et][mt] = __builtin_amdgcn_mfma_f32_16x16x32_bf16(
                    wfrag[s * 4 + mt], bf[et], acc[et][mt], 0, 0, 0);
    }

    #pragma unroll
    for (int et = 0; et < 2; ++et) {
        if (rowi[et] < nrows) {
            #pragma unroll
            for (int mt = 0; mt < 4; ++mt) {
                half4 hv;
                #pragma unroll
                for (int rr = 0; rr < 4; ++rr) hv[rr] = (_Float16)acc[et][mt][rr];
                *reinterpret_cast<half4*>(
                    &u[(size_t)rowi[et] * 128 + wh * 64 + mt * 16 + quad * 4]) = hv;
            }
        }
    }
}

// Edge phase v3: out[e] = w2 . relu(ud[row[e]] + us[col[e]]) + b2.
// 8 lanes per edge (le = lane>>3, q = lane&7), coalesced 16-lines-per-instr gathers.
// FOUR-deep software pipeline with statically-indexed register rings:
//   at sub-step k (literal):  GATH slot (k+3)&3 for chunk j+3   [idx loaded 2 steps ago]
//                             LIDX slot (k+5)&3 for chunk j+5
//                             COMP slot k        for chunk j     [gathered 3 steps ago]
// -> every gather has ~3 compute phases (>500 cy) of slack to cover the L2-miss->L3
// latency that limited the 2-deep version. All ring indices are compile-time literals
// (jb += 4 outer loop), so buffers stay in VGPRs. ~100 VGPR -> 4 waves/SIMD; grid 1024
// = 4 blocks/CU fully co-resident (no queue tail), NC = 32 chunks/block.
__global__ __launch_bounds__(256, 4) void edge_eval(
    const _Float16* __restrict__ ud, const _Float16* __restrict__ us,
    const int* __restrict__ row, const int* __restrict__ col,
    const float* __restrict__ w2, const float* __restrict__ b2,
    float* __restrict__ out, int nchunks)
{
    const int tid  = threadIdx.x;
    const int lane = tid & 63;
    const int wave = tid >> 6;
    const int le   = lane >> 3;          // edge slot 0..7
    const int q    = lane & 7;           // 16B sub-chunk 0..7
    const int lslot = wave * 8 + le;     // 0..31 within chunk

#if __has_builtin(__builtin_amdgcn_fdot2)
    half2v w2h[8];                       // w2[i*64 + q*8 + 2p .. +1] as fp16 pairs
    #pragma unroll
    for (int i = 0; i < 2; ++i)
        #pragma unroll
        for (int p = 0; p < 4; ++p) {
            half2v t;
            t[0] = (_Float16)w2[i * 64 + q * 8 + 2 * p];
            t[1] = (_Float16)w2[i * 64 + q * 8 + 2 * p + 1];
            w2h[i * 4 + p] = t;
        }
#else
    float w2r[16];
    #pragma unroll
    for (int i = 0; i < 2; ++i) {
        *reinterpret_cast<floatx4*>(&w2r[i * 8]) =
            *reinterpret_cast<const floatx4*>(&w2[i * 64 + q * 8]);
        *reinterpret_cast<floatx4*>(&w2r[i * 8 + 4]) =
            *reinterpret_cast<const floatx4*>(&w2[i * 64 + q * 8 + 4]);
    }
#endif
    const float b2v = b2[0];
    const int G = gridDim.x;
    const int b = blockIdx.x;
    const int NC = nchunks / G;          // 32, uniform (G | nchunks)

    int ridx[4], cidx[4];
    half8 Ur[4][2], Vr[4][2];

#define LIDX(slot, j)                                                          \
    if ((j) < NC) {                                                            \
        int e = (b + (j) * G) * 32 + lslot;                                    \
        ridx[slot] = row[e]; cidx[slot] = col[e];                              \
    }

#define GATH(slot, j)                                                          \
    if ((j) < NC) {                                                            \
        const _Float16* up = ud + (size_t)ridx[slot] * 128 + q * 8;            \
        const _Float16* vp = us + (size_t)cidx[slot] * 128 + q * 8;            \
        Ur[slot][0] = *reinterpret_cast<const half8*>(up);                     \
        Ur[slot][1] = *reinterpret_cast<const half8*>(up + 64);                \
        Vr[slot][0] = *reinterpret_cast<const half8*>(vp);                     \
        Vr[slot][1] = *reinterpret_cast<const half8*>(vp + 64);                \
    }

#if __has_builtin(__builtin_amdgcn_fdot2)
#define DOT(slot, accv)                                                        \
    _Pragma("unroll")                                                          \
    for (int i = 0; i < 2; ++i) {                                              \
        half8 s8 = Ur[slot][i] + Vr[slot][i];                                  \
        s8 = __builtin_elementwise_max(s8, (half8)(_Float16)0.f);              \
        _Pragma("unroll")                                                      \
        for (int p = 0; p < 4; ++p) {                                          \
            half2v pr; pr[0] = s8[2 * p]; pr[1] = s8[2 * p + 1];               \
            accv = __builtin_amdgcn_fdot2(pr, w2h[i * 4 + p], accv, false);    \
        }                                                                      \
    }
#else
#define DOT(slot, accv)                                                        \
    _Pragma("unroll")                                                          \
    for (int i = 0; i < 2; ++i) {                                              \
        half8 s8 = Ur[slot][i] + Vr[slot][i];                                  \
        s8 = __builtin_elementwise_max(s8, (half8)(_Float16)0.f);              \
        _Pragma("unroll")                                                      \
        for (int j2 = 0; j2 < 8; ++j2)                                         \
            accv += (float)s8[j2] * w2r[i * 8 + j2];                           \
    }
#endif

#define COMP(slot, j)                                                          \
    if ((j) < NC) {                                                            \
        float acc = 0.f;                                                       \
        DOT(slot, acc)                                                         \
        acc += __shfl_xor(acc, 1);                                             \
        acc += __shfl_xor(acc, 2);                                             \
        acc += __shfl_xor(acc, 4);                                             \
        if (q == 0) out[(b + (j) * G) * 32 + lslot] = acc + b2v;               \
    }

    // ---- prologue: idx 0..2, gathers 0..2, idx 3..4 ----
    LIDX(0, 0) LIDX(1, 1) LIDX(2, 2)
    GATH(0, 0) GATH(1, 1) GATH(2, 2)
    LIDX(3, 3) LIDX(0, 4)

    for (int jb = 0; jb < NC; jb += 4) {
        GATH(3, jb + 3) LIDX(1, jb + 5) COMP(0, jb)
        GATH(0, jb + 4) LIDX(2, jb + 6) COMP(1, jb + 1)
        GATH(1, jb + 5) LIDX(3, jb + 7) COMP(2, jb + 2)
        GATH(2, jb + 6) LIDX(0, jb + 8) COMP(3, jb + 3)
    }
#undef LIDX
#undef GATH
#undef DOT
#undef COMP
}

extern "C" void kernel_launch(void* const* d_in, const int* in_sizes, int n_in,
                              void* d_out, int out_size, void* d_ws, size_t ws_size,
                              hipStream_t stream) {
    const float* zd = (const float*)d_in[0];
    const float* zs = (const float*)d_in[1];
    const int*   row = (const int*)d_in[2];
    const int*   col = (const int*)d_in[3];
    const float* W1 = (const float*)d_in[4];
    const float* b1 = (const float*)d_in[5];
    const float* w2 = (const float*)d_in[6];
    const float* b2 = (const float*)d_in[7];
    float* out = (float*)d_out;

    const int nd = in_sizes[0];   // 10000*128
    const int ns = in_sizes[1];   // 15000*128
    const int E  = in_sizes[2];   // 1048576
    const int ndrows = nd / 128;
    const int nsrows = ns / 128;

    // workspace: w1t (64 KB) | ud fp16 | us fp16 = 6.47 MB
    unsigned short* w1t = (unsigned short*)d_ws;
    _Float16* ud = (_Float16*)((char*)d_ws + 128 * 256 * sizeof(unsigned short));
    _Float16* us = ud + (size_t)ndrows * 128;

    hipLaunchKernelGGL(prep_w1, dim3(128), dim3(256), 0, stream, W1, w1t);

    const int ntd = (ndrows + 63) / 64;   // 157
    const int nts = (nsrows + 63) / 64;   // 235
    hipLaunchKernelGGL(factor_gemm, dim3(ntd + nts), dim3(256), 0, stream,
                       zd, zs, w1t, b1, ud, us, ndrows, nsrows, ntd);

    const int nchunks = E / 32;           // 32768 chunks of 32 edges
    const int egrid = 1024;               // 4 blocks/CU co-resident, NC = 32
    hipLaunchKernelGGL(edge_eval, dim3(egrid), dim3(256), 0, stream,
                       ud, us, row, col, w2, b2, out, nchunks);
}

// Round 6
// 122.120 us; speedup vs baseline: 1.6735x; 1.0344x over previous
//
#include <hip/hip_runtime.h>

typedef __attribute__((ext_vector_type(8))) short short8;
typedef __attribute__((ext_vector_type(4))) float floatx4;
typedef _Float16 half8 __attribute__((ext_vector_type(8)));
typedef _Float16 half4 __attribute__((ext_vector_type(4)));
typedef _Float16 half2v __attribute__((ext_vector_type(2)));

static __device__ __forceinline__ unsigned short f2bf(float x) {
    unsigned int u = __builtin_bit_cast(unsigned int, x);
    unsigned int r = (u + 0x7FFFu + ((u >> 16) & 1u)) >> 16;
    return (unsigned short)r;
}

// W1 [256k][128n] -> w1t [128n][256k] bf16; zero the 4 class cursors.
__global__ void prep_w1(const float* __restrict__ W1, unsigned short* __restrict__ w1t,
                        unsigned* __restrict__ gcur) {
    int i = blockIdx.x * 256 + threadIdx.x;   // grid covers exactly 128*256
    int n = i >> 8;
    int k = i & 255;
    w1t[n * 256 + k] = f2bf(W1[k * 128 + n]);
    if (i < 16) gcur[i] = 0;
}

// Merged mid phase. Blocks [0, nbg): factorized GEMM (unchanged math):
//   ud[i] = zd[i] @ W1[0:128]  + 0.5*b1   (10000 x 128, fp16)
//   us[j] = zs[j] @ W1[128:256] + 0.5*b1  (15000 x 128, fp16)
// Blocks [nbg, nbg+E/2048): class-scatter. Class = (row>=5000)*2 | (col>=7500).
// Each class's gather footprint (ud-half 1.28MB + us-half 1.92MB = 3.2MB) fits one
// XCD's 4MiB L2 -> edge_eval partitions classes across XCDs. Ballot-aggregated
// compaction: 4 global atomicAdds per block; bucket-internal order is irrelevant
// (each record carries its edge id; out[eid] has exactly one writer).
__global__ __launch_bounds__(256, 2) void mid_kernel(
    const float* __restrict__ zd, const float* __restrict__ zs,
    const unsigned short* __restrict__ w1t, const float* __restrict__ b1,
    _Float16* __restrict__ ud, _Float16* __restrict__ us,
    int ndrows, int nsrows, int ntd, int nbg,
    const int* __restrict__ row, const int* __restrict__ col,
    unsigned* __restrict__ gcur, unsigned* __restrict__ rcbuf,
    unsigned* __restrict__ eidbuf, int E)
{
    if ((int)blockIdx.x < nbg) {
        // ---------------- factor GEMM ----------------
        const int tid  = threadIdx.x;
        const int lane = tid & 63;
        const int wave = tid >> 6;
        const int wh   = wave >> 1;
        const int we   = wave & 1;
        const int l15  = lane & 15;
        const int quad = lane >> 4;

        const int b = blockIdx.x;
        const bool isD = (b < ntd);
        const float* __restrict__ z = isD ? zd : zs;
        _Float16* __restrict__ u = isD ? ud : us;
        const int nrows = isD ? ndrows : nsrows;
        const int m0    = (isD ? b : b - ntd) * 64;
        const int koff0 = isD ? 0 : 128;

        short8 wfrag[16];
        #pragma unroll
        for (int s = 0; s < 4; ++s)
            #pragma unroll
            for (int mt = 0; mt < 4; ++mt)
                wfrag[s * 4 + mt] = *reinterpret_cast<const short8*>(
                    &w1t[(size_t)(wh * 64 + mt * 16 + l15) * 256 + koff0 + s * 32 + quad * 8]);

        floatx4 acc[2][4];
        #pragma unroll
        for (int mt = 0; mt < 4; ++mt) {
            floatx4 bb = *reinterpret_cast<const floatx4*>(&b1[wh * 64 + mt * 16 + quad * 4]);
            bb *= 0.5f;                   // each half contributes b1/2 -> sum = b1
            acc[0][mt] = bb;
            acc[1][mt] = bb;
        }

        int rowi[2], rowc[2];
        #pragma unroll
        for (int et = 0; et < 2; ++et) {
            rowi[et] = m0 + we * 32 + et * 16 + l15;
            rowc[et] = rowi[et] < nrows ? rowi[et] : nrows - 1;
        }

        #pragma unroll
        for (int s = 0; s < 4; ++s) {
            short8 bf[2];
            #pragma unroll
            for (int et = 0; et < 2; ++et) {
                const float* src = &z[(size_t)rowc[et] * 128 + s * 32 + quad * 8];
                floatx4 lo = *reinterpret_cast<const floatx4*>(src);
                floatx4 hi = *reinterpret_cast<const floatx4*>(src + 4);
                short8 t;
                t[0] = (short)f2bf(lo[0]); t[1] = (short)f2bf(lo[1]);
                t[2] = (short)f2bf(lo[2]); t[3] = (short)f2bf(lo[3]);
                t[4] = (short)f2bf(hi[0]); t[5] = (short)f2bf(hi[1]);
                t[6] = (short)f2bf(hi[2]); t[7] = (short)f2bf(hi[3]);
                bf[et] = t;
            }
            #pragma unroll
            for (int et = 0; et < 2; ++et)
                #pragma unroll
                for (int mt = 0; mt < 4; ++mt)
                    acc[et][mt] = __builtin_amdgcn_mfma_f32_16x16x32_bf16(
                        wfrag[s * 4 + mt], bf[et], acc[et][mt], 0, 0, 0);
        }

        #pragma unroll
        for (int et = 0; et < 2; ++et) {
            if (rowi[et] < nrows) {
                #pragma unroll
                for (int mt = 0; mt < 4; ++mt) {
                    half4 hv;
                    #pragma unroll
                    for (int rr = 0; rr < 4; ++rr) hv[rr] = (_Float16)acc[et][mt][rr];
                    *reinterpret_cast<half4*>(
                        &u[(size_t)rowi[et] * 128 + wh * 64 + mt * 16 + quad * 4]) = hv;
                }
            }
        }
    } else {
        // ---------------- class scatter ----------------
        __shared__ unsigned wl[4][4];    // [wave][class]
        __shared__ unsigned gb[4];       // block base per class
        const int tid  = threadIdx.x;
        const int lane = tid & 63;
        const int wave = tid >> 6;
        const int sb   = blockIdx.x - nbg;
        const long base = (long)sb * 2048;    // E % 2048 == 0

        unsigned rc[8], off[8];
        int cls0, cls1, cls2, cls3, cls4, cls5, cls6, cls7;
        unsigned w0 = 0, w1 = 0, w2c = 0, w3 = 0;   // per-wave running class counts

        #pragma unroll
        for (int k = 0; k < 8; ++k) {
            long e = base + wave * 512 + k * 64 + lane;   // coalesced per wave
            int r = row[e], c = col[e];
            rc[k] = (unsigned)r | ((unsigned)c << 14);
            int cl = ((r >= 5000) ? 2 : 0) | ((c >= 7500) ? 1 : 0);
            unsigned long long m0 = __ballot(cl == 0);
            unsigned long long m1 = __ballot(cl == 1);
            unsigned long long m2 = __ballot(cl == 2);
            unsigned long long m3 = __ballot(cl == 3);
            unsigned long long mlt = (1ull << lane) - 1ull;
            unsigned long long mc = (cl == 0) ? m0 : (cl == 1) ? m1 : (cl == 2) ? m2 : m3;
            unsigned wb = (cl == 0) ? w0 : (cl == 1) ? w1 : (cl == 2) ? w2c : w3;
            off[k] = wb + (unsigned)__popcll(mc & mlt);
            w0 += (unsigned)__popcll(m0); w1 += (unsigned)__popcll(m1);
            w2c += (unsigned)__popcll(m2); w3 += (unsigned)__popcll(m3);
            switch (k) {   // static stores of cls (avoid runtime-indexed reg array)
                case 0: cls0 = cl; break; case 1: cls1 = cl; break;
                case 2: cls2 = cl; break; case 3: cls3 = cl; break;
                case 4: cls4 = cl; break; case 5: cls5 = cl; break;
                case 6: cls6 = cl; break; default: cls7 = cl; break;
            }
        }
        if (lane < 4) {
            unsigned wv = (lane == 0) ? w0 : (lane == 1) ? w1 : (lane == 2) ? w2c : w3;
            wl[wave][lane] = wv;
        }
        __syncthreads();
        if (tid < 4) {
            unsigned tot = wl[0][tid] + wl[1][tid] + wl[2][tid] + wl[3][tid];
            gb[tid] = atomicAdd(&gcur[tid], tot);
        }
        __syncthreads();
        unsigned p0 = 0, p1 = 0, p2 = 0, p3 = 0;   // prefix of earlier waves
        for (int w = 0; w < 4; ++w)
            if (w < wave) { p0 += wl[w][0]; p1 += wl[w][1]; p2 += wl[w][2]; p3 += wl[w][3]; }

        #pragma unroll
        for (int k = 0; k < 8; ++k) {
            long e = base + wave * 512 + k * 64 + lane;
            int cl = (k == 0) ? cls0 : (k == 1) ? cls1 : (k == 2) ? cls2 : (k == 3) ? cls3
                   : (k == 4) ? cls4 : (k == 5) ? cls5 : (k == 6) ? cls6 : cls7;
            unsigned pre = (cl == 0) ? p0 : (cl == 1) ? p1 : (cl == 2) ? p2 : p3;
            unsigned pos = gb[cl] + pre + off[k];
            rcbuf[(size_t)cl * E + pos]  = rc[k];
            eidbuf[(size_t)cl * E + pos] = (unsigned)e;
        }
    }
}

// Edge phase v4: class-partitioned gather. Block b -> XCD b&7 (round-robin
// heuristic), class = xcd>>1, so each XCD's L2 only ever sees its class's
// 3.2MB ud/us slice -> gathers are L2-hits. 8 lanes/edge, coalesced 16B loads,
// 1-ahead rc/eid prefetch; latency hidden by 32 waves/CU of TLP (lb(256,8),
// ~50 VGPR). Wrong-mapping fallback: classes interleave -> today's behavior.
__global__ __launch_bounds__(256, 8) void edge_eval(
    const _Float16* __restrict__ ud, const _Float16* __restrict__ us,
    const unsigned* __restrict__ gcur, const unsigned* __restrict__ rcbuf,
    const unsigned* __restrict__ eidbuf,
    const float* __restrict__ w2, const float* __restrict__ b2,
    float* __restrict__ out, int E)
{
    const int tid  = threadIdx.x;
    const int lane = tid & 63;
    const int wave = tid >> 6;
    const int le   = lane >> 3;          // edge slot 0..7
    const int q    = lane & 7;           // 16B sub-chunk 0..7
    const int lslot = wave * 8 + le;     // 0..31 within chunk

    const int b    = blockIdx.x;
    const int xcd  = b & 7;
    const int cls  = xcd >> 1;
    const int sub  = ((b >> 3) << 1) | (xcd & 1);
    const int NSUB = (int)((gridDim.x >> 3) << 1);

    const unsigned n = gcur[cls];
    const int nch = (int)((n + 31u) >> 5);
    const unsigned* __restrict__ rcb = rcbuf + (size_t)cls * E;
    const unsigned* __restrict__ eib = eidbuf + (size_t)cls * E;

#if __has_builtin(__builtin_amdgcn_fdot2)
    half2v w2h[8];                       // w2[i*64 + q*8 + 2p .. +1]
    #pragma unroll
    for (int i = 0; i < 2; ++i)
        #pragma unroll
        for (int p = 0; p < 4; ++p) {
            half2v t;
            t[0] = (_Float16)w2[i * 64 + q * 8 + 2 * p];
            t[1] = (_Float16)w2[i * 64 + q * 8 + 2 * p + 1];
            w2h[i * 4 + p] = t;
        }
#else
    float w2r[16];
    #pragma unroll
    for (int i = 0; i < 2; ++i) {
        *reinterpret_cast<floatx4*>(&w2r[i * 8]) =
            *reinterpret_cast<const floatx4*>(&w2[i * 64 + q * 8]);
        *reinterpret_cast<floatx4*>(&w2r[i * 8 + 4]) =
            *reinterpret_cast<const floatx4*>(&w2[i * 64 + q * 8 + 4]);
    }
#endif
    const float b2v = b2[0];

    int t = sub;
    if (t >= nch) return;

    unsigned ei0 = (unsigned)t * 32u + (unsigned)lslot;
    bool v0 = ei0 < n;
    unsigned ci0 = v0 ? ei0 : 0u;
    unsigned rc0 = rcb[ci0];
    unsigned id0 = eib[ci0];

    while (true) {
        const int tn = t + NSUB;

        // gathers for current chunk (L2-resident slice)
        unsigned r = rc0 & 16383u, c = rc0 >> 14;
        const _Float16* up = ud + (size_t)r * 128 + q * 8;
        const _Float16* vp = us + (size_t)c * 128 + q * 8;
        half8 U0 = *reinterpret_cast<const half8*>(up);
        half8 U1 = *reinterpret_cast<const half8*>(up + 64);
        half8 V0 = *reinterpret_cast<const half8*>(vp);
        half8 V1 = *reinterpret_cast<const half8*>(vp + 64);

        // prefetch next chunk's record
        unsigned rc1 = 0, id1 = 0;
        bool v1 = false;
        if (tn < nch) {
            unsigned ei1 = (unsigned)tn * 32u + (unsigned)lslot;
            v1 = ei1 < n;
            unsigned ci1 = v1 ? ei1 : 0u;
            rc1 = rcb[ci1];
            id1 = eib[ci1];
        }

        // compute: relu(u+v) . w2  (fp16 packed add/max, f32 accumulate)
        float acc = 0.f;
        half8 s0 = U0 + V0;
        s0 = __builtin_elementwise_max(s0, (half8)(_Float16)0.f);
        half8 s1 = U1 + V1;
        s1 = __builtin_elementwise_max(s1, (half8)(_Float16)0.f);
#if __has_builtin(__builtin_amdgcn_fdot2)
        #pragma unroll
        for (int p = 0; p < 4; ++p) {
            half2v pr0; pr0[0] = s0[2 * p]; pr0[1] = s0[2 * p + 1];
            acc = __builtin_amdgcn_fdot2(pr0, w2h[p], acc, false);
            half2v pr1; pr1[0] = s1[2 * p]; pr1[1] = s1[2 * p + 1];
            acc = __builtin_amdgcn_fdot2(pr1, w2h[4 + p], acc, false);
        }
#else
        #pragma unroll
        for (int j = 0; j < 8; ++j) {
            acc += (float)s0[j] * w2r[j];
            acc += (float)s1[j] * w2r[8 + j];
        }
#endif
        acc += __shfl_xor(acc, 1);
        acc += __shfl_xor(acc, 2);
        acc += __shfl_xor(acc, 4);
        if (v0 && q == 0) out[id0] = acc + b2v;

        if (tn >= nch) break;
        t = tn; rc0 = rc1; id0 = id1; v0 = v1;
    }
}

extern "C" void kernel_launch(void* const* d_in, const int* in_sizes, int n_in,
                              void* d_out, int out_size, void* d_ws, size_t ws_size,
                              hipStream_t stream) {
    const float* zd = (const float*)d_in[0];
    const float* zs = (const float*)d_in[1];
    const int*   row = (const int*)d_in[2];
    const int*   col = (const int*)d_in[3];
    const float* W1 = (const float*)d_in[4];
    const float* b1 = (const float*)d_in[5];
    const float* w2 = (const float*)d_in[6];
    const float* b2 = (const float*)d_in[7];
    float* out = (float*)d_out;

    const int nd = in_sizes[0];   // 10000*128
    const int ns = in_sizes[1];   // 15000*128
    const int E  = in_sizes[2];   // 1048576 (multiple of 2048)
    const int ndrows = nd / 128;
    const int nsrows = ns / 128;

    // ws: w1t 64KB | ud fp16 | us fp16 | gcur(64B) | rcbuf 4*E u32 | eidbuf 4*E u32 (~39MB)
    unsigned short* w1t = (unsigned short*)d_ws;
    _Float16* ud = (_Float16*)((char*)d_ws + 128 * 256 * sizeof(unsigned short));
    _Float16* us = ud + (size_t)ndrows * 128;
    size_t off = (size_t)((char*)(us + (size_t)nsrows * 128) - (char*)d_ws);
    off = (off + 63) & ~(size_t)63;
    unsigned* gcur   = (unsigned*)((char*)d_ws + off);
    unsigned* rcbuf  = gcur + 16;
    unsigned* eidbuf = rcbuf + (size_t)4 * E;

    hipLaunchKernelGGL(prep_w1, dim3(128), dim3(256), 0, stream, W1, w1t, gcur);

    const int ntd = (ndrows + 63) / 64;   // 157
    const int nts = (nsrows + 63) / 64;   // 235
    const int nbg = ntd + nts;            // 392 GEMM blocks
    const int nsb = E / 2048;             // 512 scatter blocks
    hipLaunchKernelGGL(mid_kernel, dim3(nbg + nsb), dim3(256), 0, stream,
                       zd, zs, w1t, b1, ud, us, ndrows, nsrows, ntd, nbg,
                       row, col, gcur, rcbuf, eidbuf, E);

    hipLaunchKernelGGL(edge_eval, dim3(2048), dim3(256), 0, stream,
                       ud, us, gcur, rcbuf, eidbuf, w2, b2, out, E);
}